// Round 3
// 364.954 us; speedup vs baseline: 1.6702x; 1.6702x over previous
//
#include <hip/hip_runtime.h>

__device__ __forceinline__ float u2f(unsigned short u) {
  union { unsigned int i; float f; } v; v.i = ((unsigned)u) << 16; return v.f;
}
__device__ __forceinline__ unsigned short f2u(float f) {
  union { float f; unsigned int i; } v; v.f = f;
  unsigned int x = v.i;
  return (unsigned short)((x + 0x7fffu + ((x >> 16) & 1u)) >> 16);  // RNE bf16
}
__device__ __forceinline__ unsigned int pack2(float a, float b) {
  return (unsigned int)f2u(a) | ((unsigned int)f2u(b) << 16);
}

__device__ __forceinline__ void decode_hw(const void* Hp, const void* Wp, int& H, int& W) {
  long long h = ((const int*)Hp)[0], w = ((const int*)Wp)[0];
  if (h >= 1 && h <= 16384 && w >= 1 && w <= 16384 && h * w == 16384) { H = (int)h; W = (int)w; return; }
  float fh = ((const float*)Hp)[0], fw = ((const float*)Wp)[0];
  if (fh >= 1.f && fh <= 16384.f && fw >= 1.f && fw <= 16384.f &&
      (long long)fh * (long long)fw == 16384) { H = (int)fh; W = (int)fw; return; }
  H = 128; W = 128;
}

typedef __attribute__((ext_vector_type(4))) float f32x4;
typedef __attribute__((ext_vector_type(8))) short bf16x8;

// ---------------- prep: Bt[n][k] = bf16(W[k][n]) for the 3 weight matrices ----
__launch_bounds__(256)
__global__ void prep_kernel(const float* __restrict__ Wv, const float* __restrict__ Wo,
                            const float* __restrict__ Wa, const float* __restrict__ Wout,
                            const float* __restrict__ bo, const float* __restrict__ ba,
                            unsigned short* __restrict__ Btv,
                            unsigned short* __restrict__ Btout,
                            unsigned short* __restrict__ Btol,
                            float* __restrict__ bol)
{
  const int n = blockIdx.x;
  const int k = threadIdx.x;  // 0..255 = K
  if (n < 256) {
    Btv[n * 256 + k] = f2u(Wv[k * 256 + n]);
  } else if (n < 512) {
    const int nn = n - 256;
    Btout[nn * 256 + k] = f2u(Wout[k * 256 + nn]);
  } else {
    const int nn = n - 512;  // 0..127
    float v = (nn < 64) ? Wo[k * 64 + nn] : ((nn < 96) ? Wa[k * 32 + (nn - 64)] : 0.f);
    Btol[nn * 256 + k] = f2u(v);
    if (k == 0) bol[nn] = (nn < 64) ? bo[nn] : ((nn < 96) ? ba[nn - 64] : 0.f);
  }
}

// ---------------- MFMA GEMM: C[M][ldc] = A[M][256] @ Bt^T + bias --------------
// A: fp32 or bf16 (converted to bf16 at LDS-stage time). Bt: [BN][256] bf16,
// row n = column n of B. BM=64, BK=64, 4 waves; wave w owns cols [w*BN/4, ...).
// LDS rows padded to 72 shorts (stride 144 B = 9*16 -> 16B-aligned b128 reads,
// 2-way bank aliasing only, which is free).
template<int BN, bool ABF16, bool OUTBF16>
__launch_bounds__(256)
__global__ void mfma_gemm(const void* __restrict__ A,
                          const unsigned short* __restrict__ Bt,
                          const float* __restrict__ bias,
                          void* __restrict__ C,
                          int N, int ldc)
{
  constexpr int NF = BN / 64;  // n-frags per wave
  __shared__ __align__(16) unsigned short As[64][72];
  __shared__ __align__(16) unsigned short Bs[BN][72];
  const int tid = threadIdx.x;
  const int wid = tid >> 6, lane = tid & 63;
  const int row16 = lane & 15, kq = lane >> 4;
  const int m0 = blockIdx.x * 64;
  const int wn0 = wid * (BN / 4);

  f32x4 acc[4][NF];
  const f32x4 zero4 = {0.f, 0.f, 0.f, 0.f};
  #pragma unroll
  for (int i = 0; i < 4; ++i)
    #pragma unroll
    for (int j = 0; j < NF; ++j)
      acc[i][j] = zero4;

  const int arow = tid >> 2, aq = tid & 3;  // A-stage: 1/4 row (16 elems) per thread

  for (int k0 = 0; k0 < 256; k0 += 64) {
    // ---- stage A tile [64][64] (16 elements per thread) ----
    if constexpr (ABF16) {
      const unsigned short* ap = (const unsigned short*)A + (size_t)(m0 + arow) * 256 + k0 + aq * 16;
      *(uint4*)&As[arow][aq * 16 + 0] = *(const uint4*)(ap + 0);  // uint4 = 8 shorts
      *(uint4*)&As[arow][aq * 16 + 8] = *(const uint4*)(ap + 8);
    } else {
      const float* ap = (const float*)A + (size_t)(m0 + arow) * 256 + k0 + aq * 16;
      float4 f0 = *(const float4*)(ap + 0);
      float4 f1 = *(const float4*)(ap + 4);
      float4 g0 = *(const float4*)(ap + 8);
      float4 g1 = *(const float4*)(ap + 12);
      uint4 u0 = make_uint4(pack2(f0.x, f0.y), pack2(f0.z, f0.w), pack2(f1.x, f1.y), pack2(f1.z, f1.w));
      uint4 u1 = make_uint4(pack2(g0.x, g0.y), pack2(g0.z, g0.w), pack2(g1.x, g1.y), pack2(g1.z, g1.w));
      *(uint4*)&As[arow][aq * 16 + 0] = u0;
      *(uint4*)&As[arow][aq * 16 + 8] = u1;
    }
    // ---- stage Bt tile [BN][64]: 64 shorts per row = 8 uint4 ----
    if constexpr (BN == 256) {
      const unsigned short* bp = Bt + (size_t)tid * 256 + k0;  // 1 thread per row
      #pragma unroll
      for (int j = 0; j < 8; ++j)
        *(uint4*)&Bs[tid][j * 8] = *(const uint4*)(bp + j * 8);
    } else {  // BN == 128: 2 threads per row, 32 contiguous shorts each
      const int bn = tid >> 1, bh = tid & 1;
      const unsigned short* bp = Bt + (size_t)bn * 256 + k0 + bh * 32;
      #pragma unroll
      for (int j = 0; j < 4; ++j)
        *(uint4*)&Bs[bn][bh * 32 + j * 8] = *(const uint4*)(bp + j * 8);
    }
    __syncthreads();

    #pragma unroll
    for (int ks = 0; ks < 64; ks += 32) {
      bf16x8 af[4], bfr[NF];
      #pragma unroll
      for (int mf = 0; mf < 4; ++mf)
        af[mf] = *(const bf16x8*)&As[mf * 16 + row16][ks + kq * 8];
      #pragma unroll
      for (int nf = 0; nf < NF; ++nf)
        bfr[nf] = *(const bf16x8*)&Bs[wn0 + nf * 16 + row16][ks + kq * 8];
      #pragma unroll
      for (int mf = 0; mf < 4; ++mf)
        #pragma unroll
        for (int nf = 0; nf < NF; ++nf)
          acc[mf][nf] = __builtin_amdgcn_mfma_f32_16x16x32_bf16(af[mf], bfr[nf], acc[mf][nf], 0, 0, 0);
    }
    __syncthreads();
  }

  // ---- epilogue: C/D layout col=lane&15, row=(lane>>4)*4+r ----
  #pragma unroll
  for (int nf = 0; nf < NF; ++nf) {
    const int col = wn0 + nf * 16 + row16;
    if (col < N) {
      const float bv = bias[col];
      #pragma unroll
      for (int mf = 0; mf < 4; ++mf) {
        #pragma unroll
        for (int r = 0; r < 4; ++r) {
          const int rrow = m0 + mf * 16 + kq * 4 + r;
          const float v = acc[mf][nf][r] + bv;
          if (OUTBF16) ((unsigned short*)C)[(size_t)rrow * ldc + col] = f2u(v);
          else         ((float*)C)[(size_t)rrow * ldc + col] = v;
        }
      }
    }
  }
}

// -------- Sampler: softmax + bilinear sampling (off/logits precomputed) ------
#define RQ 8
__launch_bounds__(256)
__global__ void sample_kernel(const unsigned short* __restrict__ value, // (B,S,NH,DH) bf16
                              const float* __restrict__ offlog,         // (B*LQ,96) fp32
                              const float* __restrict__ refp,           // (B*LQ,2)
                              unsigned short* __restrict__ out,         // (B*LQ,256) bf16
                              const void* __restrict__ Hp,
                              const void* __restrict__ Wp)
{
  int H, W; decode_hw(Hp, Wp, H, W);
  const int S = H * W;
  __shared__ float off_s[RQ][64];
  __shared__ float lg_s[RQ][36];
  __shared__ float ref_s[RQ][2];
  const int tid = threadIdx.x;
  const int r0 = blockIdx.x * RQ;

  if (tid < RQ * 24) {  // 8 rows x 24 float4 = 96 floats each
    const int row = tid / 24, c4 = (tid % 24) * 4;
    float4 v = *(const float4*)(offlog + (size_t)(r0 + row) * 96 + c4);
    if (c4 < 64) *(float4*)&off_s[row][c4] = v;
    else         *(float4*)&lg_s[row][c4 - 64] = v;
  }
  if (tid < RQ * 2)
    ref_s[tid >> 1][tid & 1] = refp[(size_t)(r0 + (tid >> 1)) * 2 + (tid & 1)];
  __syncthreads();

  const int h = tid >> 5, c = tid & 31;
  const int b = r0 >> 13;                 // LQ = 8192
  const size_t vbase = (size_t)b * S * 256;
  for (int row = 0; row < RQ; ++row) {
    const int r = r0 + row;
    float lg[4];
    #pragma unroll
    for (int p = 0; p < 4; ++p) lg[p] = lg_s[row][h * 4 + p];
    float mx = fmaxf(fmaxf(lg[0], lg[1]), fmaxf(lg[2], lg[3]));
    float sum = 0.f;
    #pragma unroll
    for (int p = 0; p < 4; ++p) { lg[p] = __expf(lg[p] - mx); sum += lg[p]; }
    const float inv = 1.f / sum;
    const float rx = ref_s[row][0], ry = ref_s[row][1];
    float acc = 0.f;
    #pragma unroll
    for (int p = 0; p < 4; ++p) {
      const float x = rx * (float)W + off_s[row][h * 8 + p * 2 + 0] - 0.5f;
      const float y = ry * (float)H + off_s[row][h * 8 + p * 2 + 1] - 0.5f;
      const float xf = floorf(x), yf = floorf(y);
      const float wx = x - xf, wy = y - yf;
      const int x0 = (int)xf, y0 = (int)yf;
      float sp = 0.f;
      #pragma unroll
      for (int dy = 0; dy < 2; ++dy)
        #pragma unroll
        for (int dx = 0; dx < 2; ++dx) {
          const int yy = y0 + dy, xx = x0 + dx;
          if ((unsigned)yy < (unsigned)H && (unsigned)xx < (unsigned)W) {
            const float wgt = (dy ? wy : 1.f - wy) * (dx ? wx : 1.f - wx);
            sp += wgt * u2f(value[vbase + (size_t)(yy * W + xx) * 256 + h * 32 + c]);
          }
        }
      acc += lg[p] * inv * sp;
    }
    out[(size_t)r * 256 + h * 32 + c] = f2u(acc);
  }
}

// ---------------- Residual + LayerNorm (D=256), wave per row ----------------
__launch_bounds__(256)
__global__ void ln_kernel(const float* __restrict__ A,
                          const float* __restrict__ B2,
                          const float* __restrict__ g,
                          const float* __restrict__ be,
                          float* __restrict__ out)
{
  const size_t row = (size_t)blockIdx.x * 4 + (threadIdx.x >> 6);
  const int lane = threadIdx.x & 63;
  const size_t base = row * 256 + lane * 4;
  const float4 xa = *(const float4*)(A + base);
  const float4 xb = *(const float4*)(B2 + base);
  float x[4];
  x[0] = xa.x + xb.x; x[1] = xa.y + xb.y; x[2] = xa.z + xb.z; x[3] = xa.w + xb.w;
  float s = x[0] + x[1] + x[2] + x[3];
  float sq = x[0]*x[0] + x[1]*x[1] + x[2]*x[2] + x[3]*x[3];
  #pragma unroll
  for (int off = 32; off; off >>= 1) {
    s  += __shfl_xor(s, off);
    sq += __shfl_xor(sq, off);
  }
  const float mean = s * (1.f / 256.f);
  const float var = sq * (1.f / 256.f) - mean * mean;
  const float rstd = rsqrtf(var + 1e-5f);
  const float4 gg = *(const float4*)(g + lane * 4);
  const float4 bb = *(const float4*)(be + lane * 4);
  float4 o;
  o.x = (x[0] - mean) * rstd * gg.x + bb.x;
  o.y = (x[1] - mean) * rstd * gg.y + bb.y;
  o.z = (x[2] - mean) * rstd * gg.z + bb.z;
  o.w = (x[3] - mean) * rstd * gg.w + bb.w;
  *(float4*)(out + base) = o;
}

// LN(2*x): single read of src.
__launch_bounds__(256)
__global__ void ln2x_kernel(const float* __restrict__ A,
                            const float* __restrict__ g,
                            const float* __restrict__ be,
                            float* __restrict__ out)
{
  const size_t row = (size_t)blockIdx.x * 4 + (threadIdx.x >> 6);
  const int lane = threadIdx.x & 63;
  const size_t base = row * 256 + lane * 4;
  const float4 xa = *(const float4*)(A + base);
  float x[4];
  x[0] = 2.f * xa.x; x[1] = 2.f * xa.y; x[2] = 2.f * xa.z; x[3] = 2.f * xa.w;
  float s = x[0] + x[1] + x[2] + x[3];
  float sq = x[0]*x[0] + x[1]*x[1] + x[2]*x[2] + x[3]*x[3];
  #pragma unroll
  for (int off = 32; off; off >>= 1) {
    s  += __shfl_xor(s, off);
    sq += __shfl_xor(sq, off);
  }
  const float mean = s * (1.f / 256.f);
  const float var = sq * (1.f / 256.f) - mean * mean;
  const float rstd = rsqrtf(var + 1e-5f);
  const float4 gg = *(const float4*)(g + lane * 4);
  const float4 bb = *(const float4*)(be + lane * 4);
  float4 o;
  o.x = (x[0] - mean) * rstd * gg.x + bb.x;
  o.y = (x[1] - mean) * rstd * gg.y + bb.y;
  o.z = (x[2] - mean) * rstd * gg.z + bb.z;
  o.w = (x[3] - mean) * rstd * gg.w + bb.w;
  *(float4*)(out + base) = o;
}

extern "C" void kernel_launch(void* const* d_in, const int* in_sizes, int n_in,
                              void* d_out, int out_size, void* d_ws, size_t ws_size,
                              hipStream_t stream) {
  const float* tgt  = (const float*)d_in[0];
  const float* src  = (const float*)d_in[1];
  const float* refp = (const float*)d_in[2];
  const float* Wv   = (const float*)d_in[3];
  const float* bv   = (const float*)d_in[4];
  const float* Wo   = (const float*)d_in[5];
  const float* bo   = (const float*)d_in[6];
  const float* Wa   = (const float*)d_in[7];
  const float* ba   = (const float*)d_in[8];
  const float* Wout = (const float*)d_in[9];
  const float* bout = (const float*)d_in[10];
  const float* g1   = (const float*)d_in[11];
  const float* b1   = (const float*)d_in[12];
  const float* g2   = (const float*)d_in[13];
  const float* b2   = (const float*)d_in[14];
  const void* Hp    = d_in[15];
  const void* Wp    = d_in[16];

  // d_out: fp32, [query 8388608 | src_out 16777216] elements.
  float* q_out    = (float*)d_out;
  float* s_region = q_out + (size_t)8388608;
  float* s_out    = s_region;

  // ws layout (<= 34 MB of the proven >=46 MB):
  //   value bf16 [65536*256]   : 33.55 MB
  //   Btv  bf16 [256][256], Btout bf16 [256][256], Btol bf16 [128][256], bol f32[128]
  unsigned short* value = (unsigned short*)d_ws;
  unsigned short* Btv   = value + (size_t)16777216;
  unsigned short* Btout = Btv + 65536;
  unsigned short* Btol  = Btout + 65536;
  float*          bol   = (float*)(Btol + 32768);

  // s_region (67 MB, dead until ln2x at the end) sub-allocation:
  //   offlog fp32 [32768][96]  : floats [0, 3145728)
  //   sampled bf16 [32768][256]: floats [4194304, 8388608)
  //   aobuf fp32 [32768][256]  : floats [8388608, 16777216)
  float*          offlog  = s_region;
  unsigned short* sampled = (unsigned short*)(s_region + (size_t)4194304);
  float*          aobuf   = s_region + (size_t)8388608;

  dim3 blk(256);
  // 0. weight transpose/convert -> bf16 Bt[n][k]
  prep_kernel<<<dim3(640), blk, 0, stream>>>(Wv, Wo, Wa, Wout, bo, ba, Btv, Btout, Btol, bol);
  // 1. offlog = tgt @ [W_off|W_attn] + [b_off|b_attn]   (32768 x 96 x 256, MFMA)
  mfma_gemm<128, false, false><<<dim3(512), blk, 0, stream>>>(tgt, Btol, bol, offlog, 96, 96);
  // 2. value = src @ W_value + b_value                  (65536 x 256 x 256, MFMA) -> bf16
  mfma_gemm<256, false, true><<<dim3(1024), blk, 0, stream>>>(src, Btv, bv, value, 256, 256);
  // 3. softmax + bilinear sampling -> sampled bf16
  sample_kernel<<<dim3(32768 / RQ), blk, 0, stream>>>(value, offlog, refp, sampled, Hp, Wp);
  // 4. attn_out = sampled @ W_out + b_out               (32768 x 256 x 256, MFMA) -> fp32
  mfma_gemm<256, true, false><<<dim3(512), blk, 0, stream>>>(sampled, Btout, bout, aobuf, 256, 256);
  // 5. query = LN(tgt + attn_out) -> q_out
  ln_kernel<<<dim3(8192), blk, 0, stream>>>(tgt, aobuf, g1, b1, q_out);
  // 6. src_out = LN(2*src) -> s_out (overwrites dead offlog/sampled/aobuf)
  ln2x_kernel<<<dim3(16384), blk, 0, stream>>>(src, g2, b2, s_out);
}

// Round 4
// 301.718 us; speedup vs baseline: 2.0203x; 1.2096x over previous
//
#include <hip/hip_runtime.h>

__device__ __forceinline__ float u2f(unsigned short u) {
  union { unsigned int i; float f; } v; v.i = ((unsigned)u) << 16; return v.f;
}
__device__ __forceinline__ unsigned short f2u(float f) {
  union { float f; unsigned int i; } v; v.f = f;
  unsigned int x = v.i;
  return (unsigned short)((x + 0x7fffu + ((x >> 16) & 1u)) >> 16);  // RNE bf16
}
__device__ __forceinline__ unsigned int pack2(float a, float b) {
  return (unsigned int)f2u(a) | ((unsigned int)f2u(b) << 16);
}

__device__ __forceinline__ void decode_hw(const void* Hp, const void* Wp, int& H, int& W) {
  long long h = ((const int*)Hp)[0], w = ((const int*)Wp)[0];
  if (h >= 1 && h <= 16384 && w >= 1 && w <= 16384 && h * w == 16384) { H = (int)h; W = (int)w; return; }
  float fh = ((const float*)Hp)[0], fw = ((const float*)Wp)[0];
  if (fh >= 1.f && fh <= 16384.f && fw >= 1.f && fw <= 16384.f &&
      (long long)fh * (long long)fw == 16384) { H = (int)fh; W = (int)fw; return; }
  H = 128; W = 128;
}

typedef __attribute__((ext_vector_type(4))) float f32x4;
typedef __attribute__((ext_vector_type(8))) short bf16x8;

// ---------------- prep: Bt[n][k] = bf16(W[k][n]) for the 3 weight matrices ----
__launch_bounds__(256)
__global__ void prep_kernel(const float* __restrict__ Wv, const float* __restrict__ Wo,
                            const float* __restrict__ Wa, const float* __restrict__ Wout,
                            const float* __restrict__ bo, const float* __restrict__ ba,
                            unsigned short* __restrict__ Btv,
                            unsigned short* __restrict__ Btout,
                            unsigned short* __restrict__ Btol,
                            float* __restrict__ bol)
{
  const int n = blockIdx.x;
  const int k = threadIdx.x;  // 0..255 = K
  if (n < 256) {
    Btv[n * 256 + k] = f2u(Wv[k * 256 + n]);
  } else if (n < 512) {
    const int nn = n - 256;
    Btout[nn * 256 + k] = f2u(Wout[k * 256 + nn]);
  } else {
    const int nn = n - 512;  // 0..127
    float v = (nn < 64) ? Wo[k * 64 + nn] : ((nn < 96) ? Wa[k * 32 + (nn - 64)] : 0.f);
    Btol[nn * 256 + k] = f2u(v);
    if (k == 0) bol[nn] = (nn < 64) ? bo[nn] : ((nn < 96) ? ba[nn - 64] : 0.f);
  }
}

// ---------------- MFMA GEMM: C[M][ldc] = A[M][256] @ Bt^T + bias --------------
// LDS rows padded to 72 shorts (stride 144 B -> 16B-aligned b128, 2-way bank
// aliasing only, free). BM=64, BK=64, 4 waves.
template<int BN, bool ABF16, bool OUTBF16>
__launch_bounds__(256)
__global__ void mfma_gemm(const void* __restrict__ A,
                          const unsigned short* __restrict__ Bt,
                          const float* __restrict__ bias,
                          void* __restrict__ C,
                          int N, int ldc)
{
  constexpr int NF = BN / 64;  // n-frags per wave
  __shared__ __align__(16) unsigned short As[64][72];
  __shared__ __align__(16) unsigned short Bs[BN][72];
  const int tid = threadIdx.x;
  const int wid = tid >> 6, lane = tid & 63;
  const int row16 = lane & 15, kq = lane >> 4;
  const int m0 = blockIdx.x * 64;
  const int wn0 = wid * (BN / 4);

  f32x4 acc[4][NF];
  const f32x4 zero4 = {0.f, 0.f, 0.f, 0.f};
  #pragma unroll
  for (int i = 0; i < 4; ++i)
    #pragma unroll
    for (int j = 0; j < NF; ++j)
      acc[i][j] = zero4;

  const int arow = tid >> 2, aq = tid & 3;  // A-stage: 16 elems per thread

  for (int k0 = 0; k0 < 256; k0 += 64) {
    if constexpr (ABF16) {
      const unsigned short* ap = (const unsigned short*)A + (size_t)(m0 + arow) * 256 + k0 + aq * 16;
      *(uint4*)&As[arow][aq * 16 + 0] = *(const uint4*)(ap + 0);
      *(uint4*)&As[arow][aq * 16 + 8] = *(const uint4*)(ap + 8);
    } else {
      const float* ap = (const float*)A + (size_t)(m0 + arow) * 256 + k0 + aq * 16;
      float4 f0 = *(const float4*)(ap + 0);
      float4 f1 = *(const float4*)(ap + 4);
      float4 g0 = *(const float4*)(ap + 8);
      float4 g1 = *(const float4*)(ap + 12);
      uint4 u0 = make_uint4(pack2(f0.x, f0.y), pack2(f0.z, f0.w), pack2(f1.x, f1.y), pack2(f1.z, f1.w));
      uint4 u1 = make_uint4(pack2(g0.x, g0.y), pack2(g0.z, g0.w), pack2(g1.x, g1.y), pack2(g1.z, g1.w));
      *(uint4*)&As[arow][aq * 16 + 0] = u0;
      *(uint4*)&As[arow][aq * 16 + 8] = u1;
    }
    if constexpr (BN == 256) {
      const unsigned short* bp = Bt + (size_t)tid * 256 + k0;
      #pragma unroll
      for (int j = 0; j < 8; ++j)
        *(uint4*)&Bs[tid][j * 8] = *(const uint4*)(bp + j * 8);
    } else {  // BN == 128: 2 threads per row, 32 contiguous shorts each
      const int bn = tid >> 1, bh = tid & 1;
      const unsigned short* bp = Bt + (size_t)bn * 256 + k0 + bh * 32;
      #pragma unroll
      for (int j = 0; j < 4; ++j)
        *(uint4*)&Bs[bn][bh * 32 + j * 8] = *(const uint4*)(bp + j * 8);
    }
    __syncthreads();

    #pragma unroll
    for (int ks = 0; ks < 64; ks += 32) {
      bf16x8 af[4], bfr[NF];
      #pragma unroll
      for (int mf = 0; mf < 4; ++mf)
        af[mf] = *(const bf16x8*)&As[mf * 16 + row16][ks + kq * 8];
      #pragma unroll
      for (int nf = 0; nf < NF; ++nf)
        bfr[nf] = *(const bf16x8*)&Bs[wn0 + nf * 16 + row16][ks + kq * 8];
      #pragma unroll
      for (int mf = 0; mf < 4; ++mf)
        #pragma unroll
        for (int nf = 0; nf < NF; ++nf)
          acc[mf][nf] = __builtin_amdgcn_mfma_f32_16x16x32_bf16(af[mf], bfr[nf], acc[mf][nf], 0, 0, 0);
    }
    __syncthreads();
  }

  // C/D layout: col = lane&15, row = (lane>>4)*4 + r
  #pragma unroll
  for (int nf = 0; nf < NF; ++nf) {
    const int col = wn0 + nf * 16 + row16;
    if (col < N) {
      const float bv = bias[col];
      #pragma unroll
      for (int mf = 0; mf < 4; ++mf) {
        #pragma unroll
        for (int r = 0; r < 4; ++r) {
          const int rrow = m0 + mf * 16 + kq * 4 + r;
          const float v = acc[mf][nf][r] + bv;
          if (OUTBF16) ((unsigned short*)C)[(size_t)rrow * ldc + col] = f2u(v);
          else         ((float*)C)[(size_t)rrow * ldc + col] = v;
        }
      }
    }
  }
}

// ------- Fused GEMM (sampled @ W_out + b_out) + residual(tgt) + LayerNorm ----
// BN=256 so each block owns complete 64 rows; LN via 16-lane shfl reduce +
// 2 KB LDS cross-wave combine. Output fp32 q_out.
__launch_bounds__(256)
__global__ void gemm_ln_kernel(const unsigned short* __restrict__ A,   // sampled bf16
                               const unsigned short* __restrict__ Bt,  // Btout
                               const float* __restrict__ bias,
                               const float* __restrict__ tgt,
                               const float* __restrict__ g,
                               const float* __restrict__ be,
                               float* __restrict__ out)
{
  __shared__ __align__(16) unsigned short As[64][72];
  __shared__ __align__(16) unsigned short Bs[256][72];
  __shared__ float2 red_s[64][4];
  const int tid = threadIdx.x;
  const int wid = tid >> 6, lane = tid & 63;
  const int row16 = lane & 15, kq = lane >> 4;
  const int m0 = blockIdx.x * 64;
  const int wn0 = wid * 64;

  f32x4 acc[4][4];
  const f32x4 zero4 = {0.f, 0.f, 0.f, 0.f};
  #pragma unroll
  for (int i = 0; i < 4; ++i)
    #pragma unroll
    for (int j = 0; j < 4; ++j)
      acc[i][j] = zero4;

  const int arow = tid >> 2, aq = tid & 3;

  for (int k0 = 0; k0 < 256; k0 += 64) {
    const unsigned short* ap = A + (size_t)(m0 + arow) * 256 + k0 + aq * 16;
    *(uint4*)&As[arow][aq * 16 + 0] = *(const uint4*)(ap + 0);
    *(uint4*)&As[arow][aq * 16 + 8] = *(const uint4*)(ap + 8);
    const unsigned short* bp = Bt + (size_t)tid * 256 + k0;
    #pragma unroll
    for (int j = 0; j < 8; ++j)
      *(uint4*)&Bs[tid][j * 8] = *(const uint4*)(bp + j * 8);
    __syncthreads();

    #pragma unroll
    for (int ks = 0; ks < 64; ks += 32) {
      bf16x8 af[4], bfr[4];
      #pragma unroll
      for (int mf = 0; mf < 4; ++mf)
        af[mf] = *(const bf16x8*)&As[mf * 16 + row16][ks + kq * 8];
      #pragma unroll
      for (int nf = 0; nf < 4; ++nf)
        bfr[nf] = *(const bf16x8*)&Bs[wn0 + nf * 16 + row16][ks + kq * 8];
      #pragma unroll
      for (int mf = 0; mf < 4; ++mf)
        #pragma unroll
        for (int nf = 0; nf < 4; ++nf)
          acc[mf][nf] = __builtin_amdgcn_mfma_f32_16x16x32_bf16(af[mf], bfr[nf], acc[mf][nf], 0, 0, 0);
    }
    __syncthreads();
  }

  // x = acc + bias + tgt (in place); per-row partials over this wave's 64 cols
  float bcol[4], gcol[4], becol[4];
  #pragma unroll
  for (int nf = 0; nf < 4; ++nf) {
    const int col = wn0 + nf * 16 + row16;
    bcol[nf] = bias[col]; gcol[nf] = g[col]; becol[nf] = be[col];
  }
  #pragma unroll
  for (int mf = 0; mf < 4; ++mf) {
    #pragma unroll
    for (int r = 0; r < 4; ++r) {
      const int row = mf * 16 + kq * 4 + r;
      float s = 0.f, q = 0.f;
      #pragma unroll
      for (int nf = 0; nf < 4; ++nf) {
        const int col = wn0 + nf * 16 + row16;
        float v = acc[mf][nf][r] + bcol[nf] + tgt[(size_t)(m0 + row) * 256 + col];
        acc[mf][nf][r] = v;
        s += v; q += v * v;
      }
      #pragma unroll
      for (int off = 1; off < 16; off <<= 1) {
        s += __shfl_xor(s, off);
        q += __shfl_xor(q, off);
      }
      if (row16 == 0) red_s[row][wid] = make_float2(s, q);
    }
  }
  __syncthreads();

  #pragma unroll
  for (int mf = 0; mf < 4; ++mf) {
    #pragma unroll
    for (int r = 0; r < 4; ++r) {
      const int row = mf * 16 + kq * 4 + r;
      const float2 a0 = red_s[row][0], a1 = red_s[row][1];
      const float2 a2 = red_s[row][2], a3 = red_s[row][3];
      const float s = a0.x + a1.x + a2.x + a3.x;
      const float q = a0.y + a1.y + a2.y + a3.y;
      const float mean = s * (1.f / 256.f);
      const float var = q * (1.f / 256.f) - mean * mean;
      const float rstd = rsqrtf(var + 1e-5f);
      #pragma unroll
      for (int nf = 0; nf < 4; ++nf) {
        const int col = wn0 + nf * 16 + row16;
        out[(size_t)(m0 + row) * 256 + col] = (acc[mf][nf][r] - mean) * rstd * gcol[nf] + becol[nf];
      }
    }
  }
}

// -------- Sampler: softmax + bilinear, 4 channels/thread via ushort4 --------
#define RQ 8
__launch_bounds__(256)
__global__ void sample_kernel(const unsigned short* __restrict__ value, // (B,S,NH,DH) bf16
                              const float* __restrict__ offlog,         // (B*LQ,96) fp32
                              const float* __restrict__ refp,           // (B*LQ,2)
                              unsigned short* __restrict__ out,         // (B*LQ,256) bf16
                              const void* __restrict__ Hp,
                              const void* __restrict__ Wp)
{
  int H, W; decode_hw(Hp, Wp, H, W);
  const int S = H * W;
  __shared__ float off_s[RQ][64];
  __shared__ float lg_s[RQ][36];
  __shared__ float ref_s[RQ][2];
  const int tid = threadIdx.x;
  const int r0 = blockIdx.x * RQ;

  if (tid < RQ * 24) {  // 8 rows x 24 float4 = 96 floats each
    const int row = tid / 24, c4 = (tid % 24) * 4;
    float4 v = *(const float4*)(offlog + (size_t)(r0 + row) * 96 + c4);
    if (c4 < 64) *(float4*)&off_s[row][c4] = v;
    else         *(float4*)&lg_s[row][c4 - 64] = v;
  }
  if (tid < RQ * 2)
    ref_s[tid >> 1][tid & 1] = refp[(size_t)(r0 + (tid >> 1)) * 2 + (tid & 1)];
  __syncthreads();

  const int rs = tid >> 6;          // row slot 0..3
  const int h  = (tid >> 3) & 7;    // head
  const int cq = (tid & 7) * 4;     // channel quad
  const int b = r0 >> 13;           // LQ = 8192
  const unsigned short* vptr = value + (size_t)b * S * 256 + h * 32 + cq;

  #pragma unroll
  for (int it = 0; it < RQ / 4; ++it) {
    const int row = it * 4 + rs;
    const int r = r0 + row;
    float lg[4];
    #pragma unroll
    for (int p = 0; p < 4; ++p) lg[p] = lg_s[row][h * 4 + p];
    const float mx = fmaxf(fmaxf(lg[0], lg[1]), fmaxf(lg[2], lg[3]));
    float sum = 0.f;
    #pragma unroll
    for (int p = 0; p < 4; ++p) { lg[p] = __expf(lg[p] - mx); sum += lg[p]; }
    const float inv = 1.f / sum;
    const float rx = ref_s[row][0], ry = ref_s[row][1];
    float a0 = 0.f, a1 = 0.f, a2 = 0.f, a3 = 0.f;
    #pragma unroll
    for (int p = 0; p < 4; ++p) {
      const float x = rx * (float)W + off_s[row][h * 8 + p * 2 + 0] - 0.5f;
      const float y = ry * (float)H + off_s[row][h * 8 + p * 2 + 1] - 0.5f;
      const float xf = floorf(x), yf = floorf(y);
      const float wx = x - xf, wy = y - yf;
      const int x0 = (int)xf, y0 = (int)yf;
      const float wp = lg[p] * inv;
      #pragma unroll
      for (int dy = 0; dy < 2; ++dy)
        #pragma unroll
        for (int dx = 0; dx < 2; ++dx) {
          const int yy = y0 + dy, xx = x0 + dx;
          if ((unsigned)yy < (unsigned)H && (unsigned)xx < (unsigned)W) {
            const float wgt = wp * (dy ? wy : 1.f - wy) * (dx ? wx : 1.f - wx);
            const ushort4 v4 = *(const ushort4*)(vptr + (size_t)(yy * W + xx) * 256);
            a0 += wgt * u2f(v4.x);
            a1 += wgt * u2f(v4.y);
            a2 += wgt * u2f(v4.z);
            a3 += wgt * u2f(v4.w);
          }
        }
    }
    ushort4 o4;
    o4.x = f2u(a0); o4.y = f2u(a1); o4.z = f2u(a2); o4.w = f2u(a3);
    *(ushort4*)(out + (size_t)r * 256 + h * 32 + cq) = o4;
  }
}

// LN(2*x): single read of src.
__launch_bounds__(256)
__global__ void ln2x_kernel(const float* __restrict__ A,
                            const float* __restrict__ g,
                            const float* __restrict__ be,
                            float* __restrict__ out)
{
  const size_t row = (size_t)blockIdx.x * 4 + (threadIdx.x >> 6);
  const int lane = threadIdx.x & 63;
  const size_t base = row * 256 + lane * 4;
  const float4 xa = *(const float4*)(A + base);
  float x[4];
  x[0] = 2.f * xa.x; x[1] = 2.f * xa.y; x[2] = 2.f * xa.z; x[3] = 2.f * xa.w;
  float s = x[0] + x[1] + x[2] + x[3];
  float sq = x[0]*x[0] + x[1]*x[1] + x[2]*x[2] + x[3]*x[3];
  #pragma unroll
  for (int off = 32; off; off >>= 1) {
    s  += __shfl_xor(s, off);
    sq += __shfl_xor(sq, off);
  }
  const float mean = s * (1.f / 256.f);
  const float var = sq * (1.f / 256.f) - mean * mean;
  const float rstd = rsqrtf(var + 1e-5f);
  const float4 gg = *(const float4*)(g + lane * 4);
  const float4 bb = *(const float4*)(be + lane * 4);
  float4 o;
  o.x = (x[0] - mean) * rstd * gg.x + bb.x;
  o.y = (x[1] - mean) * rstd * gg.y + bb.y;
  o.z = (x[2] - mean) * rstd * gg.z + bb.z;
  o.w = (x[3] - mean) * rstd * gg.w + bb.w;
  *(float4*)(out + base) = o;
}

extern "C" void kernel_launch(void* const* d_in, const int* in_sizes, int n_in,
                              void* d_out, int out_size, void* d_ws, size_t ws_size,
                              hipStream_t stream) {
  const float* tgt  = (const float*)d_in[0];
  const float* src  = (const float*)d_in[1];
  const float* refp = (const float*)d_in[2];
  const float* Wv   = (const float*)d_in[3];
  const float* bv   = (const float*)d_in[4];
  const float* Wo   = (const float*)d_in[5];
  const float* bo   = (const float*)d_in[6];
  const float* Wa   = (const float*)d_in[7];
  const float* ba   = (const float*)d_in[8];
  const float* Wout = (const float*)d_in[9];
  const float* bout = (const float*)d_in[10];
  const float* g1   = (const float*)d_in[11];
  const float* b1   = (const float*)d_in[12];
  const float* g2   = (const float*)d_in[13];
  const float* b2   = (const float*)d_in[14];
  const void* Hp    = d_in[15];
  const void* Wp    = d_in[16];

  // d_out: fp32, [query 8388608 | src_out 16777216] elements.
  float* q_out    = (float*)d_out;
  float* s_region = q_out + (size_t)8388608;
  float* s_out    = s_region;

  // ws layout: value bf16 [65536*256] (33.55 MB) + Bt matrices + bol
  unsigned short* value = (unsigned short*)d_ws;
  unsigned short* Btv   = value + (size_t)16777216;
  unsigned short* Btout = Btv + 65536;
  unsigned short* Btol  = Btout + 65536;
  float*          bol   = (float*)(Btol + 32768);

  // s_region (67 MB, dead until ln2x at the end):
  //   offlog fp32 [32768][96]  : floats [0, 3145728)
  //   sampled bf16 [32768][256]: floats [4194304, 8388608)
  float*          offlog  = s_region;
  unsigned short* sampled = (unsigned short*)(s_region + (size_t)4194304);

  dim3 blk(256);
  // 0. weight transpose/convert -> bf16 Bt[n][k]
  prep_kernel<<<dim3(640), blk, 0, stream>>>(Wv, Wo, Wa, Wout, bo, ba, Btv, Btout, Btol, bol);
  // 1. offlog = tgt @ [W_off|W_attn] + bias   (32768 x 96 x 256, MFMA)
  mfma_gemm<128, false, false><<<dim3(512), blk, 0, stream>>>(tgt, Btol, bol, offlog, 96, 96);
  // 2. value = src @ W_value + b_value        (65536 x 256 x 256, MFMA) -> bf16
  mfma_gemm<256, false, true><<<dim3(1024), blk, 0, stream>>>(src, Btv, bv, value, 256, 256);
  // 3. softmax + bilinear sampling -> sampled bf16
  sample_kernel<<<dim3(32768 / RQ), blk, 0, stream>>>(value, offlog, refp, sampled, Hp, Wp);
  // 4. query = LN(tgt + sampled @ W_out + b_out) -> q_out  (fused GEMM+LN)
  gemm_ln_kernel<<<dim3(512), blk, 0, stream>>>(sampled, Btout, bout, tgt, g1, b1, q_out);
  // 5. src_out = LN(2*src) -> s_out (overwrites dead offlog/sampled)
  ln2x_kernel<<<dim3(16384), blk, 0, stream>>>(src, g2, b2, s_out);
}